// Round 1
// baseline (1379.603 us; speedup 1.0000x reference)
//
#include <hip/hip_runtime.h>

#define S_TOT 2000
#define H 64

// Kernel A: rel_encoded[s][j] = mask(s) * (b2[j] + sum_k relu(b1 + rel_row @ W1^T)[s][k] * W2[j][k])
// 4 rows per block, 256 threads (wave w handles local row w).
__global__ __launch_bounds__(256) void mlp_kernel(
    const int* __restrict__ d_sidx,
    const float* __restrict__ rel,     // [S, S, H]
    const float* __restrict__ W1,      // [H, H]
    const float* __restrict__ b1,      // [H]
    const float* __restrict__ W2,      // [H, H]
    const float* __restrict__ b2,      // [H]
    float* __restrict__ relenc)        // [S, H] output
{
    // pitch-65 padding: LDS bank = (j*65 + k) % 32 = (j + k) % 32 -> 2 lanes/bank (free)
    __shared__ float sW1[H * 65];
    __shared__ float sW2[H * 65];
    __shared__ float srow[4][H];
    __shared__ float sh[4][H];

    const int t = threadIdx.x;

    for (int idx = t; idx < H * H; idx += 256) {
        const int r = idx >> 6, c = idx & 63;
        sW1[r * 65 + c] = W1[idx];
        sW2[r * 65 + c] = W2[idx];
    }

    const int sidx = d_sidx[0];
    const float* relbase = rel + (size_t)sidx * S_TOT * H;
    const int s0 = blockIdx.x * 4;

    for (int idx = t; idx < 4 * H; idx += 256) {
        srow[idx >> 6][idx & 63] = relbase[(size_t)s0 * H + idx];
    }
    __syncthreads();

    const int lr = t >> 6;   // local row 0..3 (one wave per row)
    const int j  = t & 63;   // output feature

    // h[lr][j] = relu(b1[j] + sum_k srow[lr][k] * W1[j][k])
    float acc = b1[j];
    #pragma unroll
    for (int k = 0; k < H; ++k)
        acc = fmaf(srow[lr][k], sW1[j * 65 + k], acc);  // srow: wave-broadcast (free)
    acc = fmaxf(acc, 0.0f);
    sh[lr][j] = acc;
    __syncthreads();

    // out[s][j] = b2[j] + sum_k h[lr][k] * W2[j][k]
    float o = b2[j];
    #pragma unroll
    for (int k = 0; k < H; ++k)
        o = fmaf(sh[lr][k], sW2[j * 65 + k], o);

    const int s = s0 + lr;
    if (s == sidx) o = 0.0f;   // mask: exclude i == stock_idx
    relenc[s * H + j] = o;
}

// Kernel B: out[b][h] = sum_s enc[b][s][h] * relenc[s][h]
// One block per batch element. Thread t: h-quad (t&15)*4, s-stripe t>>4.
// Per iteration a wave reads 4 consecutive s-rows (1 KiB contiguous, float4/lane).
__global__ __launch_bounds__(256) void reduce_kernel(
    const float* __restrict__ enc,     // [B, S, H]
    const float* __restrict__ relenc,  // [S, H]
    float* __restrict__ out)           // [B, H]
{
    const int b = blockIdx.x;
    const int t = threadIdx.x;
    const int hq   = (t & 15) << 2;  // 0,4,...,60
    const int srow = t >> 4;         // 0..15

    const float* ebase = enc + (size_t)b * S_TOT * H;

    float4 acc = make_float4(0.f, 0.f, 0.f, 0.f);
    for (int s = srow; s < S_TOT; s += 16) {   // 2000 / 16 = 125 iters exactly
        const float4 e = *(const float4*)(ebase + s * H + hq);
        const float4 r = *(const float4*)(relenc + s * H + hq);
        acc.x = fmaf(e.x, r.x, acc.x);
        acc.y = fmaf(e.y, r.y, acc.y);
        acc.z = fmaf(e.z, r.z, acc.z);
        acc.w = fmaf(e.w, r.w, acc.w);
    }

    __shared__ float part[16][H];
    *(float4*)&part[srow][hq] = acc;
    __syncthreads();

    if (t < H) {
        float sum = 0.f;
        #pragma unroll
        for (int r = 0; r < 16; ++r) sum += part[r][t];
        out[b * H + t] = sum;
    }
}

extern "C" void kernel_launch(void* const* d_in, const int* in_sizes, int n_in,
                              void* d_out, int out_size, void* d_ws, size_t ws_size,
                              hipStream_t stream) {
    const int*   d_sidx = (const int*)d_in[0];
    const float* enc    = (const float*)d_in[1];   // [B, S, H]
    const float* rel    = (const float*)d_in[2];   // [S, S, H]
    const float* W1     = (const float*)d_in[3];
    const float* b1     = (const float*)d_in[4];
    const float* W2     = (const float*)d_in[5];
    const float* b2     = (const float*)d_in[6];
    float* out    = (float*)d_out;
    float* relenc = (float*)d_ws;                  // [S, H] = 512 KB scratch

    const int B = in_sizes[1] / (S_TOT * H);       // 1024

    mlp_kernel<<<S_TOT / 4, 256, 0, stream>>>(d_sidx, rel, W1, b1, W2, b2, relenc);
    reduce_kernel<<<B, 256, 0, stream>>>(enc, relenc, out);
}